// Round 1
// baseline (751.831 us; speedup 1.0000x reference)
//
#include <hip/hip_runtime.h>

#define B_ 2048
#define S_ 512
#define D_ 128
#define H_ 64
#define O_ 8
#define EPS 1e-5f

#define CHUNK 16
#define NCHUNK (S_ / CHUNK)   // 32
#define ROWS 8                // batch rows per block (was 16): grid 256 -> all CUs active
#define PSTRIDE 68            // floats per row-slot: 16B-aligned, low-conflict

typedef __attribute__((ext_vector_type(8))) short bf16x8;
typedef __attribute__((ext_vector_type(4))) float f32x4;

// pack two f32 -> two bf16 (round-half-up)
__device__ __forceinline__ unsigned pk_bf16(float a, float b) {
  unsigned ua = __builtin_bit_cast(unsigned, a) + 0x8000u;
  unsigned ub = __builtin_bit_cast(unsigned, b) + 0x8000u;
  return (ua >> 16) | (ub & 0xffff0000u);
}

__device__ __forceinline__ bf16x8 pack8(f32x4 a, f32x4 b) {
  union { bf16x8 v; unsigned u[4]; } t;
  t.u[0] = pk_bf16(a[0], a[1]);
  t.u[1] = pk_bf16(a[2], a[3]);
  t.u[2] = pk_bf16(b[0], b[1]);
  t.u[3] = pk_bf16(b[2], b[3]);
  return t.v;
}

// Producer/consumer block: 8 batch rows (MFMA cols 0..7; cols 8..15 carry
// garbage that stays confined to those columns), 8 waves.
//   waves 0..6: projection P_t = bias + W_ih * x_t^T for a 16-step chunk,
//               written to double-buffered LDS in MFMA C-layout (f32).
//   wave 7:     serial recurrence h = relu(W_hh*h + P_t), LDS-only reads.
// Sigma trick (verified R2 of prior session): W_hh packed with k-order
// sigma(32kt+8q+4a+e)=16(2kt+a)+4q+e so the MFMA C/D regs ARE the next
// step's B-fragment (Bh0=pack8(acc0,acc1), Bh1=pack8(acc2,acc3)).
// Epilogue: bn1 batch stats (sum, sumsq per feature) fused via shfl + atomics.
__global__ __launch_bounds__(512, 2) void rnn_fused(
    const float* __restrict__ x, const float* __restrict__ h0,
    const float* __restrict__ W_ih, const float* __restrict__ W_hh,
    const float* __restrict__ b_ih, const float* __restrict__ b_hh,
    float* __restrict__ hT, float* __restrict__ ws) {
  extern __shared__ float Plds[];   // [2][CHUNK][ROWS][PSTRIDE]
  const int tid = threadIdx.x;
  const int w = tid >> 6;           // wave id 0..7
  const int lane = tid & 63;
  const int q = lane >> 4;          // quad 0..3
  const int c = lane & 15;          // column = batch-row slot (valid: c<ROWS)
  const bool rv = (c < ROWS);       // row-valid lane
  const int row = blockIdx.x * ROWS + c;                   // deref only if rv
  const int rowc = blockIdx.x * ROWS + (c & (ROWS - 1));   // clamped (safe)

  // ---------------- producer state (waves 0..6) ----------------
  const float* xrow = x + (size_t)row * (S_ * D_) + q * 8;  // addr only; deref if rv
  bf16x8 Aih[4][4];
  f32x4 bias[4];
  // ---------------- consumer state (wave 7) ----------------
  bf16x8 Ahh[4][2];
  bf16x8 Bh[2];
  f32x4 acc[4];

  if (w < 7) {
    // W_ih -> A-frags, standard k-order: A[m=16jt+c][k=32kt+8q+e]
    // (A rows are FEATURES -> all 16 c-lanes valid)
#pragma unroll
    for (int jt = 0; jt < 4; ++jt)
#pragma unroll
      for (int kt = 0; kt < 4; ++kt) {
        const float* p = W_ih + (jt * 16 + c) * D_ + kt * 32 + q * 8;
        Aih[jt][kt] = pack8(*(const f32x4*)p, *(const f32x4*)(p + 4));
      }
#pragma unroll
    for (int jt = 0; jt < 4; ++jt) {
      f32x4 bi = *(const f32x4*)(b_ih + jt * 16 + q * 4);
      f32x4 bh = *(const f32x4*)(b_hh + jt * 16 + q * 4);
      bias[jt] = bi + bh;
    }
  } else {
    // W_hh -> A-frags in SIGMA k-order (rows are features; all c valid)
#pragma unroll
    for (int jt = 0; jt < 4; ++jt)
#pragma unroll
      for (int kt = 0; kt < 2; ++kt) {
        const float* p = W_hh + (jt * 16 + c) * H_ + kt * 32 + q * 4;
        Ahh[jt][kt] = pack8(*(const f32x4*)p, *(const f32x4*)(p + 16));
      }
    // h0 as sigma-order B-frags (clamped row: duplicate reads for c>=ROWS)
    const float* h0r = h0 + (size_t)rowc * H_;
#pragma unroll
    for (int kt = 0; kt < 2; ++kt)
      Bh[kt] = pack8(*(const f32x4*)(h0r + kt * 32 + q * 4),
                     *(const f32x4*)(h0r + kt * 32 + 16 + q * 4));
  }

  f32x4 xb[2][8];
#pragma unroll
  for (int i = 0; i < 2; ++i)
#pragma unroll
    for (int j = 0; j < 8; ++j) xb[i][j] = (f32x4){0.f, 0.f, 0.f, 0.f};

  auto loadx = [&](f32x4* d, int t) {
    if (!rv) return;                       // cols >= ROWS: keep zeros
    const float* p = xrow + (size_t)t * D_;
#pragma unroll
    for (int kt = 0; kt < 4; ++kt) {
      d[2 * kt]     = *(const f32x4*)(p + kt * 32);
      d[2 * kt + 1] = *(const f32x4*)(p + kt * 32 + 4);
    }
  };

  // producer: compute+store step s of chunk (from staged regs) into buf
  auto pstep = [&](const f32x4* xd, int s, int buf) {
    bf16x8 Bx[4];
#pragma unroll
    for (int kt = 0; kt < 4; ++kt) Bx[kt] = pack8(xd[2 * kt], xd[2 * kt + 1]);
    f32x4 a[4];
#pragma unroll
    for (int jt = 0; jt < 4; ++jt) a[jt] = bias[jt];
#pragma unroll
    for (int kt = 0; kt < 4; ++kt)
#pragma unroll
      for (int jt = 0; jt < 4; ++jt)
        a[jt] = __builtin_amdgcn_mfma_f32_16x16x32_bf16(Aih[jt][kt], Bx[kt], a[jt], 0, 0, 0);
    if (rv) {
      float* dst = Plds + ((size_t)(buf * CHUNK + s) * ROWS + c) * PSTRIDE + q * 4;
#pragma unroll
      for (int jt = 0; jt < 4; ++jt)
        *(f32x4*)(dst + jt * 16) = a[jt];
    }
  };

  // producer: whole chunk ck into buffer buf (steps w, w+7, w+14)
  const int ns = (CHUNK - 1 - w) / 7 + 1;   // 3 for w<2 else 2
  auto produce = [&](int ck, int buf) {
    const int t0 = ck * CHUNK;
    loadx(xb[0], t0 + w);
#pragma unroll
    for (int i = 0; i < 3; ++i) {
      if (i < ns) {
        if (i + 1 < ns) loadx(xb[(i + 1) & 1], t0 + w + 7 * (i + 1));
        pstep(xb[i & 1], w + 7 * i, buf);
      }
    }
  };

  // consumer: run CHUNK recurrence steps from buffer buf
  auto consume = [&](int buf) {
    const float* Pb = Plds + ((size_t)buf * CHUNK * ROWS + (c & (ROWS - 1))) * PSTRIDE + q * 4;
    f32x4 accP[4];
#pragma unroll
    for (int jt = 0; jt < 4; ++jt) accP[jt] = *(const f32x4*)(Pb + jt * 16);
#pragma unroll 1
    for (int s = 0; s < CHUNK; ++s) {
      f32x4 accN[4];
#pragma unroll
      for (int jt = 0; jt < 4; ++jt) accN[jt] = accP[jt];
      if (s + 1 < CHUNK) {
        const float* Pn = Pb + (size_t)(s + 1) * ROWS * PSTRIDE;
#pragma unroll
        for (int jt = 0; jt < 4; ++jt) accN[jt] = *(const f32x4*)(Pn + jt * 16);
      }
#pragma unroll
      for (int jt = 0; jt < 4; ++jt)
        acc[jt] = __builtin_amdgcn_mfma_f32_16x16x32_bf16(Ahh[jt][0], Bh[0], accP[jt], 0, 0, 0);
#pragma unroll
      for (int jt = 0; jt < 4; ++jt)
        acc[jt] = __builtin_amdgcn_mfma_f32_16x16x32_bf16(Ahh[jt][1], Bh[1], acc[jt], 0, 0, 0);
#pragma unroll
      for (int jt = 0; jt < 4; ++jt)
#pragma unroll
        for (int e = 0; e < 4; ++e)
          acc[jt][e] = __builtin_fmaxf(acc[jt][e], 0.0f);
      Bh[0] = pack8(acc[0], acc[1]);
      Bh[1] = pack8(acc[2], acc[3]);
#pragma unroll
      for (int jt = 0; jt < 4; ++jt) accP[jt] = accN[jt];
    }
  };

  // ---- pipeline: producers stay one chunk ahead ----
  if (w < 7) produce(0, 0);
  __syncthreads();
  for (int ck = 0; ck < NCHUNK; ++ck) {
    if (w < 7) {
      if (ck + 1 < NCHUNK) produce(ck + 1, (ck + 1) & 1);
    } else {
      consume(ck & 1);
    }
    __syncthreads();
  }

  if (w == 7) {
    if (rv) {
      float* op = hT + (size_t)row * H_;
#pragma unroll
      for (int jt = 0; jt < 4; ++jt)
        *(f32x4*)(op + jt * 16 + q * 4) = acc[jt];
    }
    // fused bn1 batch stats: per-feature sum and sumsq over this block's rows.
    // Rows live in lane bits 0..2 (c<8); butterfly-reduce those bits, then
    // lane c==0 of each quad owns features 16*jt + 4*q + e.
#pragma unroll
    for (int jt = 0; jt < 4; ++jt)
#pragma unroll
      for (int e = 0; e < 4; ++e) {
        float v = rv ? acc[jt][e] : 0.f;
        float vv = v * v;
#pragma unroll
        for (int m = 1; m < 8; m <<= 1) {
          v  += __shfl_xor(v,  m, 64);
          vv += __shfl_xor(vv, m, 64);
        }
        if (c == 0) {
          atomicAdd(&ws[jt * 16 + q * 4 + e], v);
          atomicAdd(&ws[64 + jt * 16 + q * 4 + e], vv);
        }
      }
  }
}

// ---- head: bn1 apply + fc1 + relu, z1 to ws, bn2 partial stats ----
__global__ void fc1_bn2(const float* __restrict__ hT, const float* __restrict__ bn1_g,
                        const float* __restrict__ bn1_b, const float* __restrict__ fc1_W,
                        const float* __restrict__ fc1_b, float* __restrict__ ws) {
  __shared__ float sh[1024], sw[1024], sc[64], sf[64], zz[256];
  int tid = threadIdx.x;
  int base = blockIdx.x * 1024;            // 16 rows * 64
  for (int i = tid; i < 1024; i += 256) { sh[i] = hT[base + i]; sw[i] = fc1_W[i]; }
  if (tid < 64) {
    float m = ws[tid] * (1.f / B_);
    float v = ws[64 + tid] * (1.f / B_) - m * m;
    float scl = bn1_g[tid] * rsqrtf(v + EPS);
    sc[tid] = scl;
    sf[tid] = bn1_b[tid] - m * scl;
  }
  __syncthreads();
  int r = tid >> 4, f = tid & 15;
  float a = fc1_b[f];
#pragma unroll 16
  for (int j = 0; j < 64; ++j)
    a += (sh[r * 64 + j] * sc[j] + sf[j]) * sw[f * 64 + j];
  a = fmaxf(a, 0.f);
  ws[160 + blockIdx.x * 256 + tid] = a;    // z1[(r0+r)*16+f]
  zz[tid] = a;
  __syncthreads();
  if (tid < 16) {
    float s = 0.f, s2 = 0.f;
    for (int rr = 0; rr < 16; ++rr) { float v = zz[rr * 16 + tid]; s += v; s2 += v * v; }
    atomicAdd(&ws[128 + tid], s);
    atomicAdd(&ws[144 + tid], s2);
  }
}

// ---- head: bn2 apply + fc2 -> out ----
__global__ void fc2_out(const float* __restrict__ ws, const float* __restrict__ bn2_g,
                        const float* __restrict__ bn2_b, const float* __restrict__ fc2_W,
                        const float* __restrict__ fc2_b, float* __restrict__ out) {
  __shared__ float sc2[16], sf2[16], w2[128], b2[8];
  int tid = threadIdx.x;
  if (tid < 16) {
    float m = ws[128 + tid] * (1.f / B_);
    float v = ws[144 + tid] * (1.f / B_) - m * m;
    float scl = bn2_g[tid] * rsqrtf(v + EPS);
    sc2[tid] = scl;
    sf2[tid] = bn2_b[tid] - m * scl;
  }
  if (tid < 128) w2[tid] = fc2_W[tid];
  if (tid < 8) b2[tid] = fc2_b[tid];
  __syncthreads();
  int gid = blockIdx.x * 256 + tid;
  int r = gid >> 3, o = gid & 7;
  const float* z = ws + 160 + r * 16;
  float a = b2[o];
#pragma unroll
  for (int f = 0; f < 16; ++f)
    a += (z[f] * sc2[f] + sf2[f]) * w2[o * 16 + f];
  out[gid] = a;
}

extern "C" void kernel_launch(void* const* d_in, const int* in_sizes, int n_in,
                              void* d_out, int out_size, void* d_ws, size_t ws_size,
                              hipStream_t stream) {
  (void)in_sizes; (void)n_in; (void)out_size; (void)ws_size;
  const float* x     = (const float*)d_in[0];
  const float* h0    = (const float*)d_in[1];
  const float* W_ih  = (const float*)d_in[2];
  const float* W_hh  = (const float*)d_in[3];
  const float* b_ih  = (const float*)d_in[4];
  const float* b_hh  = (const float*)d_in[5];
  const float* bn1_g = (const float*)d_in[6];
  const float* bn1_b = (const float*)d_in[7];
  const float* fc1_W = (const float*)d_in[8];
  const float* fc1_b = (const float*)d_in[9];
  const float* bn2_g = (const float*)d_in[10];
  const float* bn2_b = (const float*)d_in[11];
  const float* fc2_W = (const float*)d_in[12];
  const float* fc2_b = (const float*)d_in[13];

  float* out = (float*)d_out;
  float* hT  = out + B_ * O_;      // hidden-state output region, also head input
  float* ws  = (float*)d_ws;       // [0:64]sum1 [64:128]sq1 [128:144]sum2 [144:160]sq2 [160:+32768]z1

  const int pbytes = 2 * CHUNK * ROWS * PSTRIDE * 4;   // 69632 B dynamic LDS
  hipFuncSetAttribute((const void*)rnn_fused,
                      hipFuncAttributeMaxDynamicSharedMemorySize, pbytes);

  hipMemsetAsync(d_ws, 0, 160 * sizeof(float), stream);
  rnn_fused<<<B_ / ROWS, 512, pbytes, stream>>>(x, h0, W_ih, W_hh, b_ih, b_hh, hT, ws);
  fc1_bn2<<<128, 256, 0, stream>>>(hT, bn1_g, bn1_b, fc1_W, fc1_b, ws);
  fc2_out<<<64, 256, 0, stream>>>(ws, bn2_g, bn2_b, fc2_W, fc2_b, out);
}